// Round 2
// baseline (485.047 us; speedup 1.0000x reference)
//
#include <hip/hip_runtime.h>
#include <hip/hip_bf16.h>
#include <math.h>

#define B_  32
#define S_  512
#define D_  512
#define E_  8
#define H_  2048
#define O_  512

typedef __bf16 bf16x8 __attribute__((ext_vector_type(8)));
typedef float  f32x4  __attribute__((ext_vector_type(4)));

#define GL2LDS(src, dst) \
  __builtin_amdgcn_global_load_lds((const __attribute__((address_space(1))) void*)(src), \
                                   (__attribute__((address_space(3))) void*)(dst), 16, 0, 0)

__device__ __forceinline__ float gelu_exact(float v) {
  return 0.5f * v * (1.0f + erff(v * 0.70710678118654752f));
}

// ---------------- pooling + gating (unchanged, proven) ----------------
__global__ __launch_bounds__(256) void pool_gate_kernel(
    const float* __restrict__ x, const float* __restrict__ attn_w,
    const float* __restrict__ attn_b, const float* __restrict__ gate_w,
    const float* __restrict__ gate_b, int* __restrict__ gidx, float* __restrict__ gwt)
{
  __shared__ float sc[512];
  __shared__ float pooled[512];
  __shared__ float red[8];
  const int tid = threadIdx.x;
  const int b = blockIdx.x;
  const float* xb = x + (size_t)b * S_ * D_;
  const float ab = attn_b[0];

  for (int s = tid; s < S_; s += 256) {
    const float4* xr = (const float4*)(xb + (size_t)s * D_);
    const float4* wr = (const float4*)attn_w;
    float acc = 0.f;
    for (int i = 0; i < D_ / 4; ++i) {
      float4 xv = xr[i], wv = wr[i];
      acc += xv.x * wv.x + xv.y * wv.y + xv.z * wv.z + xv.w * wv.w;
    }
    sc[s] = acc + ab;
  }
  __syncthreads();

  float m = fmaxf(sc[tid], sc[tid + 256]);
  for (int off = 32; off; off >>= 1) m = fmaxf(m, __shfl_down(m, off));
  if ((tid & 63) == 0) red[tid >> 6] = m;
  __syncthreads();
  if (tid == 0) red[0] = fmaxf(fmaxf(red[0], red[1]), fmaxf(red[2], red[3]));
  __syncthreads();
  m = red[0];
  float e0 = expf(sc[tid] - m), e1 = expf(sc[tid + 256] - m);
  float ssum = e0 + e1;
  for (int off = 32; off; off >>= 1) ssum += __shfl_down(ssum, off);
  if ((tid & 63) == 0) red[4 + (tid >> 6)] = ssum;
  __syncthreads();
  if (tid == 0) red[4] = red[4] + red[5] + red[6] + red[7];
  __syncthreads();
  float inv = 1.f / red[4];
  sc[tid] = e0 * inv;
  sc[tid + 256] = e1 * inv;
  __syncthreads();

  float p0 = 0.f, p1 = 0.f;
  for (int s = 0; s < S_; ++s) {
    float awv = sc[s];
    p0 += awv * xb[(size_t)s * D_ + tid];
    p1 += awv * xb[(size_t)s * D_ + tid + 256];
  }
  pooled[tid] = p0;
  pooled[tid + 256] = p1;
  __syncthreads();

  if (tid < E_) {
    float z = gate_b[tid];
    for (int d = 0; d < D_; ++d) z += pooled[d] * gate_w[d * E_ + tid];
    red[tid] = z;
  }
  __syncthreads();
  if (tid == 0) {
    float zmax = red[0];
    for (int i = 1; i < E_; ++i) zmax = fmaxf(zmax, red[i]);
    float ge[E_]; float zs = 0.f;
    for (int i = 0; i < E_; ++i) { ge[i] = expf(red[i] - zmax); zs += ge[i]; }
    for (int i = 0; i < E_; ++i) ge[i] /= zs;
    int i0 = 0;
    for (int i = 1; i < E_; ++i) if (ge[i] > ge[i0]) i0 = i;
    int i1 = -1;
    for (int i = 0; i < E_; ++i) if (i != i0 && (i1 < 0 || ge[i] > ge[i1])) i1 = i;
    float denom = ge[i0] + ge[i1] + 1e-9f;
    gidx[b * 2 + 0] = i0; gidx[b * 2 + 1] = i1;
    gwt[b * 2 + 0] = ge[i0] / denom; gwt[b * 2 + 1] = ge[i1] / denom;
  }
}

// ---------------- x -> bf16 ----------------
__global__ void cast_x_kernel(const float* __restrict__ in, ushort* __restrict__ outp, int n) {
  int i = blockIdx.x * blockDim.x + threadIdx.x;
  const int n4 = n >> 2;
  for (; i < n4; i += gridDim.x * blockDim.x) {
    float4 v = ((const float4*)in)[i];
    ushort4 o;
    o.x = __builtin_bit_cast(unsigned short, __float2bfloat16(v.x));
    o.y = __builtin_bit_cast(unsigned short, __float2bfloat16(v.y));
    o.z = __builtin_bit_cast(unsigned short, __float2bfloat16(v.z));
    o.w = __builtin_bit_cast(unsigned short, __float2bfloat16(v.w));
    ((ushort4*)outp)[i] = o;
  }
}

// ---------------- [z][R][C] f32 -> [z][C][R] bf16 ----------------
__global__ void transpose_cast_kernel(const float* __restrict__ in,
                                      __hip_bfloat16* __restrict__ outT, int R, int C)
{
  __shared__ float tile[32][33];
  const int z = blockIdx.z;
  const float* inz = in + (size_t)z * R * C;
  __hip_bfloat16* outz = outT + (size_t)z * R * C;
  const int c0 = blockIdx.x * 32, r0 = blockIdx.y * 32;
  const int tx = threadIdx.x, ty = threadIdx.y;
#pragma unroll
  for (int jj = 0; jj < 4; ++jj) {
    int r = r0 + ty + jj * 8;
    tile[ty + jj * 8][tx] = inz[(size_t)r * C + c0 + tx];
  }
  __syncthreads();
#pragma unroll
  for (int jj = 0; jj < 4; ++jj) {
    int c = c0 + ty + jj * 8;
    outz[(size_t)c * R + r0 + tx] = __float2bfloat16(tile[tx][ty + jj * 8]);
  }
}

// =====================================================================
// 256x256 tile, BK=64, 512 threads (8 waves = 2 feature-halves x 4 s-quarters),
// double-buffered 128 KiB LDS, 4-phase K-step with counted vmcnt + setprio.
// A operand = weight rows (k-contig), B operand = data rows (k-contig).
// D row follows operand A (feature dim), col follows operand B (s dim) —
// verified on HW by round-1's passing kernel.
// LDS tile layout: rows of 128B, XOR-swizzle byte ^= ((row&7)<<4) applied to
// the GLOBAL source at stage time and again on ds_read (involution, rule #21).
// =====================================================================
__device__ __forceinline__ void gemm256(const char* __restrict__ Ag, const char* __restrict__ Bg,
                                        const int ldb, const int NT, char* lds, f32x4 (&acc)[8][4])
{
  const int tid = threadIdx.x;
  const int l = tid & 63;
  const int w = tid >> 6;
  const int wr = w >> 2;                 // 0..1 : feature half (128 rows)
  const int wc = w & 3;                  // 0..3 : s quarter (64 rows)
  const int lr = l & 15;
  const int hi16 = ((l >> 4) & 3) << 4;  // k-byte sub-offset
  const int axor = (lr & 7) << 4;
  const int k0 = (0   + hi16) ^ axor;
  const int k1 = (64  + hi16) ^ axor;
  const int abase = wr * 16384 + lr * 128;            // A region starts at 0
  const int bbase = 32768 + wc * 8192 + lr * 128;     // B region at 32KB

  // stage coords: per half (16KB = 128 rows x 128B), load i in {0,1}:
  //   dst off = i*8192 + tid*16 ; row = i*64 + (tid>>3) ; col = (tid&7)*16
  const int rw = tid >> 3;
  const int cs = ((tid & 7) << 4) ^ ((rw & 7) << 4);  // inverse-swizzled source col
  const char* sA00 = Ag + (size_t)(  0 +  0 + rw) * ldb + cs;
  const char* sA01 = Ag + (size_t)(  0 + 64 + rw) * ldb + cs;
  const char* sA10 = Ag + (size_t)(128 +  0 + rw) * ldb + cs;
  const char* sA11 = Ag + (size_t)(128 + 64 + rw) * ldb + cs;
  const char* sB00 = Bg + (size_t)(  0 +  0 + rw) * ldb + cs;
  const char* sB01 = Bg + (size_t)(  0 + 64 + rw) * ldb + cs;
  const char* sB10 = Bg + (size_t)(128 +  0 + rw) * ldb + cs;
  const char* sB11 = Bg + (size_t)(128 + 64 + rw) * ldb + cs;
  const int dst = tid * 16;

  // ---- prologue: stage all 4 halves of tile 0 into buf0 ----
  GL2LDS(sA00, lds + dst);            GL2LDS(sA01, lds +  8192 + dst);
  GL2LDS(sA10, lds + 16384 + dst);    GL2LDS(sA11, lds + 24576 + dst);
  GL2LDS(sB00, lds + 32768 + dst);    GL2LDS(sB01, lds + 40960 + dst);
  GL2LDS(sB10, lds + 49152 + dst);    GL2LDS(sB11, lds + 57344 + dst);
  sA00 += 128; sA01 += 128; sA10 += 128; sA11 += 128;
  sB00 += 128; sB01 += 128; sB10 += 128; sB11 += 128;

  for (int t = 0; t < NT; ++t) {
    char* cur = lds + ((t & 1) << 16);
    char* nxt = lds + (((t + 1) & 1) << 16);
    const bool pre = (t + 1 < NT);
    bf16x8 bf[4][2];
    bf16x8 af[2][2];

    // ---------------- phase 0 ----------------
    if (pre) { GL2LDS(sA00, nxt + dst); GL2LDS(sA01, nxt + 8192 + dst); }
    if (pre) asm volatile("s_waitcnt vmcnt(2)" ::: "memory");   // tile t fully landed; next h0 in flight
    else     asm volatile("s_waitcnt vmcnt(0)" ::: "memory");
    __builtin_amdgcn_s_barrier();
    __builtin_amdgcn_sched_barrier(0);
#pragma unroll
    for (int n = 0; n < 4; ++n) {
      bf[n][0] = *(const bf16x8*)(cur + bbase + n * 2048 + k0);
      bf[n][1] = *(const bf16x8*)(cur + bbase + n * 2048 + k1);
    }
    af[0][0] = *(const bf16x8*)(cur + abase + 0 * 2048 + k0);
    af[0][1] = *(const bf16x8*)(cur + abase + 0 * 2048 + k1);
    af[1][0] = *(const bf16x8*)(cur + abase + 1 * 2048 + k0);
    af[1][1] = *(const bf16x8*)(cur + abase + 1 * 2048 + k1);
    __builtin_amdgcn_s_setprio(1);
#pragma unroll
    for (int rr = 0; rr < 2; ++rr)
#pragma unroll
      for (int n = 0; n < 4; ++n)
#pragma unroll
        for (int kh = 0; kh < 2; ++kh)
          acc[0 + rr][n] = __builtin_amdgcn_mfma_f32_16x16x32_bf16(af[rr][kh], bf[n][kh], acc[0 + rr][n], 0, 0, 0);
    __builtin_amdgcn_s_setprio(0);
    __builtin_amdgcn_s_barrier();

    // ---------------- phase 1 ----------------
    if (pre) { GL2LDS(sA10, nxt + 16384 + dst); GL2LDS(sA11, nxt + 24576 + dst); }
    af[0][0] = *(const bf16x8*)(cur + abase + 2 * 2048 + k0);
    af[0][1] = *(const bf16x8*)(cur + abase + 2 * 2048 + k1);
    af[1][0] = *(const bf16x8*)(cur + abase + 3 * 2048 + k0);
    af[1][1] = *(const bf16x8*)(cur + abase + 3 * 2048 + k1);
    __builtin_amdgcn_s_setprio(1);
#pragma unroll
    for (int rr = 0; rr < 2; ++rr)
#pragma unroll
      for (int n = 0; n < 4; ++n)
#pragma unroll
        for (int kh = 0; kh < 2; ++kh)
          acc[2 + rr][n] = __builtin_amdgcn_mfma_f32_16x16x32_bf16(af[rr][kh], bf[n][kh], acc[2 + rr][n], 0, 0, 0);
    __builtin_amdgcn_s_setprio(0);
    __builtin_amdgcn_s_barrier();

    // ---------------- phase 2 ----------------
    if (pre) { GL2LDS(sB00, nxt + 32768 + dst); GL2LDS(sB01, nxt + 40960 + dst); }
    af[0][0] = *(const bf16x8*)(cur + abase + 4 * 2048 + k0);
    af[0][1] = *(const bf16x8*)(cur + abase + 4 * 2048 + k1);
    af[1][0] = *(const bf16x8*)(cur + abase + 5 * 2048 + k0);
    af[1][1] = *(const bf16x8*)(cur + abase + 5 * 2048 + k1);
    __builtin_amdgcn_s_setprio(1);
#pragma unroll
    for (int rr = 0; rr < 2; ++rr)
#pragma unroll
      for (int n = 0; n < 4; ++n)
#pragma unroll
        for (int kh = 0; kh < 2; ++kh)
          acc[4 + rr][n] = __builtin_amdgcn_mfma_f32_16x16x32_bf16(af[rr][kh], bf[n][kh], acc[4 + rr][n], 0, 0, 0);
    __builtin_amdgcn_s_setprio(0);
    __builtin_amdgcn_s_barrier();

    // ---------------- phase 3 ----------------
    if (pre) { GL2LDS(sB10, nxt + 49152 + dst); GL2LDS(sB11, nxt + 57344 + dst); }
    af[0][0] = *(const bf16x8*)(cur + abase + 6 * 2048 + k0);
    af[0][1] = *(const bf16x8*)(cur + abase + 6 * 2048 + k1);
    af[1][0] = *(const bf16x8*)(cur + abase + 7 * 2048 + k0);
    af[1][1] = *(const bf16x8*)(cur + abase + 7 * 2048 + k1);
    __builtin_amdgcn_s_setprio(1);
#pragma unroll
    for (int rr = 0; rr < 2; ++rr)
#pragma unroll
      for (int n = 0; n < 4; ++n)
#pragma unroll
        for (int kh = 0; kh < 2; ++kh)
          acc[6 + rr][n] = __builtin_amdgcn_mfma_f32_16x16x32_bf16(af[rr][kh], bf[n][kh], acc[6 + rr][n], 0, 0, 0);
    __builtin_amdgcn_s_setprio(0);
    __builtin_amdgcn_sched_barrier(0);   // pin reads/MFMA above the tile-boundary barrier
    __builtin_amdgcn_s_barrier();        // all reads of cur done -> next iter may overwrite it

    if (pre) {
      sA00 += 128; sA01 += 128; sA10 += 128; sA11 += 128;
      sB00 += 128; sB01 += 128; sB10 += 128; sB11 += 128;
    }
  }
}

// ---------------- GEMM1: H[p][s][h] = gelu(x @ w1 + b1), bf16 ----------------
__global__ __launch_bounds__(512, 2) void gemm1_kernel(
    const __hip_bfloat16* __restrict__ Xb, const __hip_bfloat16* __restrict__ W1T,
    const float* __restrict__ b1, __hip_bfloat16* __restrict__ Hbuf,
    const int* __restrict__ gidx)
{
  extern __shared__ char lds[];
  const int p = blockIdx.y;
  const int b = p >> 1;
  const int e = gidx[p];
  const int sc0 = (blockIdx.x >> 3) * 256;
  const int h0  = (blockIdx.x & 7) * 256;
  const char* Ag = (const char*)(W1T + ((size_t)e * H_ + h0) * D_);
  const char* Bg = (const char*)(Xb + ((size_t)b * S_ + sc0) * D_);
  f32x4 acc[8][4] = {};
  gemm256(Ag, Bg, D_ * 2, D_ / 64, lds, acc);

  const int tid = threadIdx.x, l = tid & 63, w = tid >> 6;
  const int wr = w >> 2, wc = w & 3, lr = l & 15, hi4 = ((l >> 4) & 3) << 2;
  const float* b1e = b1 + (size_t)e * H_ + h0;
  __hip_bfloat16* Hp = Hbuf + (size_t)p * S_ * H_;
#pragma unroll
  for (int r = 0; r < 8; ++r) {
    const int hl = wr * 128 + r * 16 + hi4;          // feature offset, multiple of 4
    const float4 bias = *(const float4*)(b1e + hl);
#pragma unroll
    for (int n = 0; n < 4; ++n) {
      const int sl = sc0 + wc * 64 + n * 16 + lr;    // s row
      ushort4 ov;
      ov.x = __builtin_bit_cast(unsigned short, __float2bfloat16(gelu_exact(acc[r][n][0] + bias.x)));
      ov.y = __builtin_bit_cast(unsigned short, __float2bfloat16(gelu_exact(acc[r][n][1] + bias.y)));
      ov.z = __builtin_bit_cast(unsigned short, __float2bfloat16(gelu_exact(acc[r][n][2] + bias.z)));
      ov.w = __builtin_bit_cast(unsigned short, __float2bfloat16(gelu_exact(acc[r][n][3] + bias.w)));
      *(ushort4*)(Hp + (size_t)sl * H_ + h0 + hl) = ov;
    }
  }
}

// ---------------- GEMM2: out[b][s][o] += g * gelu(H @ w2 + b2) ----------------
__global__ __launch_bounds__(512, 2) void gemm2_kernel(
    const __hip_bfloat16* __restrict__ Hbuf, const __hip_bfloat16* __restrict__ W2T,
    const float* __restrict__ b2, float* __restrict__ out,
    const int* __restrict__ gidx, const float* __restrict__ gwt)
{
  extern __shared__ char lds[];
  const int p = blockIdx.y;
  const int b = p >> 1;
  const int e = gidx[p];
  const float gw = gwt[p];
  const int sc0 = (blockIdx.x >> 1) * 256;
  const int o0  = (blockIdx.x & 1) * 256;
  const char* Ag = (const char*)(W2T + ((size_t)e * O_ + o0) * H_);
  const char* Bg = (const char*)(Hbuf + ((size_t)p * S_ + sc0) * H_);
  f32x4 acc[8][4] = {};
  gemm256(Ag, Bg, H_ * 2, H_ / 64, lds, acc);

  const int tid = threadIdx.x, l = tid & 63, w = tid >> 6;
  const int wr = w >> 2, wc = w & 3, lr = l & 15, hi4 = ((l >> 4) & 3) << 2;
  const float* b2e = b2 + (size_t)e * O_ + o0;
#pragma unroll
  for (int r = 0; r < 8; ++r) {
    const int ol = wr * 128 + r * 16 + hi4;          // out-feature offset
    const float4 bias = *(const float4*)(b2e + ol);
#pragma unroll
    for (int n = 0; n < 4; ++n) {
      const int sl = sc0 + wc * 64 + n * 16 + lr;
      float* dst = out + ((size_t)b * S_ + sl) * O_ + o0 + ol;
      atomicAdd(dst + 0, gelu_exact(acc[r][n][0] + bias.x) * gw);
      atomicAdd(dst + 1, gelu_exact(acc[r][n][1] + bias.y) * gw);
      atomicAdd(dst + 2, gelu_exact(acc[r][n][2] + bias.z) * gw);
      atomicAdd(dst + 3, gelu_exact(acc[r][n][3] + bias.w) * gw);
    }
  }
}

// ---------------- sentinel (ws too small signal) ----------------
__global__ void sentinel_kernel(float* out, int n) {
  int i = blockIdx.x * blockDim.x + threadIdx.x;
  for (; i < n; i += gridDim.x * blockDim.x) out[i] = 1.0e6f;
}

extern "C" void kernel_launch(void* const* d_in, const int* in_sizes, int n_in,
                              void* d_out, int out_size, void* d_ws, size_t ws_size,
                              hipStream_t stream)
{
  const float* x      = (const float*)d_in[0];
  const float* attn_w = (const float*)d_in[1];
  const float* attn_b = (const float*)d_in[2];
  const float* gate_w = (const float*)d_in[3];
  const float* gate_b = (const float*)d_in[4];
  const float* w1     = (const float*)d_in[5];
  const float* b1     = (const float*)d_in[6];
  const float* w2     = (const float*)d_in[7];
  const float* b2     = (const float*)d_in[8];
  float* out = (float*)d_out;

  char* ws = (char*)d_ws;
  const size_t OFF_GIDX = 0;
  const size_t OFF_GWT  = 256;
  const size_t OFF_X    = 512;
  const size_t SZ_X     = (size_t)B_ * S_ * D_ * 2;   // 16 MB
  const size_t OFF_W1T  = OFF_X + SZ_X;
  const size_t SZ_W1T   = (size_t)E_ * H_ * D_ * 2;   // 16 MB
  const size_t OFF_W2T  = OFF_W1T + SZ_W1T;
  const size_t SZ_W2T   = (size_t)E_ * O_ * H_ * 2;   // 16 MB
  const size_t OFF_H    = OFF_W2T + SZ_W2T;
  const size_t PAIR_H   = (size_t)S_ * H_ * 2;        // 2 MB per (b,slot) pair

  if (OFF_H + 64 * PAIR_H > ws_size) {
    hipLaunchKernelGGL(sentinel_kernel, dim3(256), dim3(256), 0, stream, out, out_size);
    return;
  }

  int*   gidx = (int*)(ws + OFF_GIDX);
  float* gwt  = (float*)(ws + OFF_GWT);
  __hip_bfloat16* xb   = (__hip_bfloat16*)(ws + OFF_X);
  __hip_bfloat16* w1T  = (__hip_bfloat16*)(ws + OFF_W1T);
  __hip_bfloat16* w2T  = (__hip_bfloat16*)(ws + OFF_W2T);
  __hip_bfloat16* Hbuf = (__hip_bfloat16*)(ws + OFF_H);

  // 128 KiB dynamic LDS opt-in (idempotent host-side call; not stream-ordered)
  (void)hipFuncSetAttribute((const void*)gemm1_kernel, hipFuncAttributeMaxDynamicSharedMemorySize, 131072);
  (void)hipFuncSetAttribute((const void*)gemm2_kernel, hipFuncAttributeMaxDynamicSharedMemorySize, 131072);

  hipLaunchKernelGGL(pool_gate_kernel, dim3(B_), dim3(256), 0, stream,
                     x, attn_w, attn_b, gate_w, gate_b, gidx, gwt);
  hipLaunchKernelGGL(cast_x_kernel, dim3(2048), dim3(256), 0, stream,
                     x, (ushort*)xb, B_ * S_ * D_);
  hipLaunchKernelGGL(transpose_cast_kernel, dim3(H_ / 32, D_ / 32, E_), dim3(32, 8), 0, stream,
                     w1, w1T, D_, H_);
  hipLaunchKernelGGL(transpose_cast_kernel, dim3(O_ / 32, H_ / 32, E_), dim3(32, 8), 0, stream,
                     w2, w2T, H_, O_);
  hipMemsetAsync(d_out, 0, (size_t)out_size * sizeof(float), stream);

  // all 64 (batch,slot) pairs in one launch each; stream order gives gemm1->gemm2 dependency
  hipLaunchKernelGGL(gemm1_kernel, dim3(16, 64), dim3(512), 131072, stream,
                     xb, w1T, b1, Hbuf, gidx);
  hipLaunchKernelGGL(gemm2_kernel, dim3(4, 64), dim3(512), 131072, stream,
                     Hbuf, w2T, b2, out, gidx, gwt);
}

// Round 3
// 342.504 us; speedup vs baseline: 1.4162x; 1.4162x over previous
//
#include <hip/hip_runtime.h>
#include <hip/hip_bf16.h>
#include <math.h>

#define B_  32
#define S_  512
#define D_  512
#define E_  8
#define H_  2048
#define O_  512

typedef __bf16 bf16x8 __attribute__((ext_vector_type(8)));
typedef float  f32x4  __attribute__((ext_vector_type(4)));

#define GL2LDS(src, dst) \
  __builtin_amdgcn_global_load_lds((const __attribute__((address_space(1))) void*)(src), \
                                   (__attribute__((address_space(3))) void*)(dst), 16, 0, 0)

__device__ __forceinline__ float gelu_exact(float v) {
  return 0.5f * v * (1.0f + erff(v * 0.70710678118654752f));
}

// ---------------- pooling + gating (unchanged, proven) ----------------
__global__ __launch_bounds__(256) void pool_gate_kernel(
    const float* __restrict__ x, const float* __restrict__ attn_w,
    const float* __restrict__ attn_b, const float* __restrict__ gate_w,
    const float* __restrict__ gate_b, int* __restrict__ gidx, float* __restrict__ gwt)
{
  __shared__ float sc[512];
  __shared__ float pooled[512];
  __shared__ float red[8];
  const int tid = threadIdx.x;
  const int b = blockIdx.x;
  const float* xb = x + (size_t)b * S_ * D_;
  const float ab = attn_b[0];

  for (int s = tid; s < S_; s += 256) {
    const float4* xr = (const float4*)(xb + (size_t)s * D_);
    const float4* wr = (const float4*)attn_w;
    float acc = 0.f;
    for (int i = 0; i < D_ / 4; ++i) {
      float4 xv = xr[i], wv = wr[i];
      acc += xv.x * wv.x + xv.y * wv.y + xv.z * wv.z + xv.w * wv.w;
    }
    sc[s] = acc + ab;
  }
  __syncthreads();

  float m = fmaxf(sc[tid], sc[tid + 256]);
  for (int off = 32; off; off >>= 1) m = fmaxf(m, __shfl_down(m, off));
  if ((tid & 63) == 0) red[tid >> 6] = m;
  __syncthreads();
  if (tid == 0) red[0] = fmaxf(fmaxf(red[0], red[1]), fmaxf(red[2], red[3]));
  __syncthreads();
  m = red[0];
  float e0 = expf(sc[tid] - m), e1 = expf(sc[tid + 256] - m);
  float ssum = e0 + e1;
  for (int off = 32; off; off >>= 1) ssum += __shfl_down(ssum, off);
  if ((tid & 63) == 0) red[4 + (tid >> 6)] = ssum;
  __syncthreads();
  if (tid == 0) red[4] = red[4] + red[5] + red[6] + red[7];
  __syncthreads();
  float inv = 1.f / red[4];
  sc[tid] = e0 * inv;
  sc[tid + 256] = e1 * inv;
  __syncthreads();

  float p0 = 0.f, p1 = 0.f;
  for (int s = 0; s < S_; ++s) {
    float awv = sc[s];
    p0 += awv * xb[(size_t)s * D_ + tid];
    p1 += awv * xb[(size_t)s * D_ + tid + 256];
  }
  pooled[tid] = p0;
  pooled[tid + 256] = p1;
  __syncthreads();

  if (tid < E_) {
    float z = gate_b[tid];
    for (int d = 0; d < D_; ++d) z += pooled[d] * gate_w[d * E_ + tid];
    red[tid] = z;
  }
  __syncthreads();
  if (tid == 0) {
    float zmax = red[0];
    for (int i = 1; i < E_; ++i) zmax = fmaxf(zmax, red[i]);
    float ge[E_]; float zs = 0.f;
    for (int i = 0; i < E_; ++i) { ge[i] = expf(red[i] - zmax); zs += ge[i]; }
    for (int i = 0; i < E_; ++i) ge[i] /= zs;
    int i0 = 0;
    for (int i = 1; i < E_; ++i) if (ge[i] > ge[i0]) i0 = i;
    int i1 = -1;
    for (int i = 0; i < E_; ++i) if (i != i0 && (i1 < 0 || ge[i] > ge[i1])) i1 = i;
    float denom = ge[i0] + ge[i1] + 1e-9f;
    gidx[b * 2 + 0] = i0; gidx[b * 2 + 1] = i1;
    gwt[b * 2 + 0] = ge[i0] / denom; gwt[b * 2 + 1] = ge[i1] / denom;
  }
}

// ---------------- sort the 64 (b,slot) pairs by expert (for XCD L2 locality) ----
__global__ void psort_kernel(const int* __restrict__ gidx, int* __restrict__ psort) {
  if (threadIdx.x == 0 && blockIdx.x == 0) {
    int cnt[E_];
    for (int e = 0; e < E_; ++e) cnt[e] = 0;
    for (int p = 0; p < 2 * B_; ++p) cnt[gidx[p]]++;
    int pos[E_]; int s = 0;
    for (int e = 0; e < E_; ++e) { pos[e] = s; s += cnt[e]; }
    for (int p = 0; p < 2 * B_; ++p) psort[pos[gidx[p]]++] = p;
  }
}

// ---------------- x -> bf16 ----------------
__global__ void cast_x_kernel(const float* __restrict__ in, ushort* __restrict__ outp, int n) {
  int i = blockIdx.x * blockDim.x + threadIdx.x;
  const int n4 = n >> 2;
  for (; i < n4; i += gridDim.x * blockDim.x) {
    float4 v = ((const float4*)in)[i];
    ushort4 o;
    o.x = __builtin_bit_cast(unsigned short, __float2bfloat16(v.x));
    o.y = __builtin_bit_cast(unsigned short, __float2bfloat16(v.y));
    o.z = __builtin_bit_cast(unsigned short, __float2bfloat16(v.z));
    o.w = __builtin_bit_cast(unsigned short, __float2bfloat16(v.w));
    ((ushort4*)outp)[i] = o;
  }
}

// ---------------- [z][R][C] f32 -> [z][C][R] bf16 ----------------
__global__ void transpose_cast_kernel(const float* __restrict__ in,
                                      __hip_bfloat16* __restrict__ outT, int R, int C)
{
  __shared__ float tile[32][33];
  const int z = blockIdx.z;
  const float* inz = in + (size_t)z * R * C;
  __hip_bfloat16* outz = outT + (size_t)z * R * C;
  const int c0 = blockIdx.x * 32, r0 = blockIdx.y * 32;
  const int tx = threadIdx.x, ty = threadIdx.y;
#pragma unroll
  for (int jj = 0; jj < 4; ++jj) {
    int r = r0 + ty + jj * 8;
    tile[ty + jj * 8][tx] = inz[(size_t)r * C + c0 + tx];
  }
  __syncthreads();
#pragma unroll
  for (int jj = 0; jj < 4; ++jj) {
    int c = c0 + ty + jj * 8;
    outz[(size_t)c * R + r0 + tx] = __float2bfloat16(tile[tx][ty + jj * 8]);
  }
}

// =====================================================================
// GEMM core: 128(s-rows of A=data) x 256(rows of B=weights -> output cols),
// BK=64, 512 threads = 8 waves (2 s-halves x 4 col-quarters), acc[4][4].
// 3-deep LDS ring (3 x 48 KiB): while computing tile t, stage tile t+2
// into the buffer freed at end of tile t-1. Counted vmcnt: at tile t's
// first phase, allow {t+1's 6 loads + 3 just issued} = vmcnt(9) in flight,
// so tile t's loads (issued 4-6 phases earlier) are drained without ever
// waiting on recent loads. Two phases per tile (kh=0 / kh=1), 16 MFMA each,
// with setprio around the MFMA cluster.
// LDS rows are 128B; XOR-swizzle byte^=((row&7)<<4) applied to the GLOBAL
// source column at stage time and again on ds_read (involution, rule #21).
// =====================================================================
__device__ __forceinline__ void gemm128x256(const char* __restrict__ Ag, const char* __restrict__ Bg,
                                            const int lda, const int ldbb, const int NT,
                                            char* lds, f32x4 (&acc)[4][4])
{
  const int tid = threadIdx.x;
  const int l = tid & 63;
  const int w = tid >> 6;
  const int wr = w >> 2;                  // s-half 0..1 (64 rows)
  const int wc = w & 3;                   // col-quarter 0..3 (64 cols)
  const int lr = l & 15;
  const int kc16 = ((l >> 4) & 3) << 4;   // 0,16,32,48 bytes within 64B k-half
  const int swz = (lr & 7) << 4;
  const int kA = kc16 ^ swz;              // kh=0
  const int kB = (64 + kc16) ^ swz;       // kh=1
  const int aoff = (wr * 64 + lr) * 128;            // A region at buffer+0
  const int boff = 16384 + (wc * 64 + lr) * 128;    // B region at buffer+16K

  // staging: 6 chunks of 8 KB (A:2, B:4); per thread 16B
  const int rw = tid >> 3;                              // 0..63 row within chunk
  const int cs = ((tid & 7) << 4) ^ ((rw & 7) << 4);    // inverse-swizzled src col
  const int dst = tid * 16;
  const char* pA0 = Ag + (size_t)(rw      ) * lda  + cs;
  const char* pA1 = Ag + (size_t)(rw +  64) * lda  + cs;
  const char* pB0 = Bg + (size_t)(rw      ) * ldbb + cs;
  const char* pB1 = Bg + (size_t)(rw +  64) * ldbb + cs;
  const char* pB2 = Bg + (size_t)(rw + 128) * ldbb + cs;
  const char* pB3 = Bg + (size_t)(rw + 192) * ldbb + cs;

  // ---- prologue: stage tiles 0 (buf0) and 1 (buf1) ----
  {
    char* q0 = lds;
    GL2LDS(pA0, q0 + dst);          GL2LDS(pA1, q0 + 8192 + dst);
    GL2LDS(pB0, q0 + 16384 + dst);  GL2LDS(pB1, q0 + 24576 + dst);
    GL2LDS(pB2, q0 + 32768 + dst);  GL2LDS(pB3, q0 + 40960 + dst);
    char* q1 = lds + 49152;
    GL2LDS(pA0 + 128, q1 + dst);          GL2LDS(pA1 + 128, q1 + 8192 + dst);
    GL2LDS(pB0 + 128, q1 + 16384 + dst);  GL2LDS(pB1 + 128, q1 + 24576 + dst);
    GL2LDS(pB2 + 128, q1 + 32768 + dst);  GL2LDS(pB3 + 128, q1 + 40960 + dst);
    pA0 += 256; pA1 += 256; pB0 += 256; pB1 += 256; pB2 += 256; pB3 += 256;
  }

  for (int t = 0; t < NT; ++t) {
    char* cur = lds + (t % 3) * 49152;
    char* nb  = lds + ((t + 2) % 3) * 49152;
    const bool pre = (t + 2 < NT);

    // ---------------- phase A (kh=0) ----------------
    if (pre) {
      GL2LDS(pA0, nb + dst);
      GL2LDS(pA1, nb + 8192 + dst);
      GL2LDS(pB0, nb + 16384 + dst);
    }
    if (pre)             asm volatile("s_waitcnt vmcnt(9)" ::: "memory");
    else if (t + 1 < NT) asm volatile("s_waitcnt vmcnt(6)" ::: "memory");
    else                 asm volatile("s_waitcnt vmcnt(0)" ::: "memory");
    __builtin_amdgcn_s_barrier();
    __builtin_amdgcn_sched_barrier(0);
    {
      bf16x8 af[4], bfv[4];
#pragma unroll
      for (int r = 0; r < 4; ++r) af[r]  = *(const bf16x8*)(cur + aoff + r * 2048 + kA);
#pragma unroll
      for (int n = 0; n < 4; ++n) bfv[n] = *(const bf16x8*)(cur + boff + n * 2048 + kA);
      __builtin_amdgcn_s_setprio(1);
#pragma unroll
      for (int r = 0; r < 4; ++r)
#pragma unroll
        for (int n = 0; n < 4; ++n)
          acc[r][n] = __builtin_amdgcn_mfma_f32_16x16x32_bf16(af[r], bfv[n], acc[r][n], 0, 0, 0);
      __builtin_amdgcn_s_setprio(0);
    }
    __builtin_amdgcn_sched_barrier(0);
    __builtin_amdgcn_s_barrier();

    // ---------------- phase B (kh=1) ----------------
    if (pre) {
      GL2LDS(pB1, nb + 24576 + dst);
      GL2LDS(pB2, nb + 32768 + dst);
      GL2LDS(pB3, nb + 40960 + dst);
      pA0 += 128; pA1 += 128; pB0 += 128; pB1 += 128; pB2 += 128; pB3 += 128;
    }
    {
      bf16x8 af[4], bfv[4];
#pragma unroll
      for (int r = 0; r < 4; ++r) af[r]  = *(const bf16x8*)(cur + aoff + r * 2048 + kB);
#pragma unroll
      for (int n = 0; n < 4; ++n) bfv[n] = *(const bf16x8*)(cur + boff + n * 2048 + kB);
      __builtin_amdgcn_s_setprio(1);
#pragma unroll
      for (int r = 0; r < 4; ++r)
#pragma unroll
        for (int n = 0; n < 4; ++n)
          acc[r][n] = __builtin_amdgcn_mfma_f32_16x16x32_bf16(af[r], bfv[n], acc[r][n], 0, 0, 0);
      __builtin_amdgcn_s_setprio(0);
    }
    __builtin_amdgcn_sched_barrier(0);
    __builtin_amdgcn_s_barrier();
  }
}

// ---------------- GEMM1: H[p][s][h] = gelu(x @ w1 + b1), bf16 ----------------
__global__ __launch_bounds__(512, 2) void gemm1_kernel(
    const __hip_bfloat16* __restrict__ Xb, const __hip_bfloat16* __restrict__ W1T,
    const float* __restrict__ b1, __hip_bfloat16* __restrict__ Hbuf,
    const int* __restrict__ gidx, const int* __restrict__ psort)
{
  extern __shared__ char lds[];
  const int nblk = gridDim.x * gridDim.y;            // 2048 (%8==0)
  const int P = blockIdx.y * gridDim.x + blockIdx.x;
  const int L = (P & 7) * (nblk >> 3) + (P >> 3);    // chunked XCD remap (bijective)
  const int pairL = L >> 5;                          // 32 tiles/pair
  const int tl = L & 31;
  const int p = psort[pairL];
  const int b = p >> 1;
  const int e = gidx[p];
  const int s0 = (tl >> 3) * 128;                    // 4 s-tiles
  const int h0 = (tl & 7) * 256;                     // 8 h-tiles
  const char* Ag = (const char*)(Xb + ((size_t)b * S_ + s0) * D_);
  const char* Bg = (const char*)(W1T + ((size_t)e * H_ + h0) * D_);
  f32x4 acc[4][4] = {};
  gemm128x256(Ag, Bg, D_ * 2, D_ * 2, D_ / 64, lds, acc);

  const int tid = threadIdx.x, l = tid & 63, w = tid >> 6;
  const int wr = w >> 2, wc = w & 3, lr = l & 15, kc4 = ((l >> 4) & 3) << 2;
  const float* b1e = b1 + (size_t)e * H_ + h0;
  __hip_bfloat16* Hp = Hbuf + (size_t)p * S_ * H_ + h0;
#pragma unroll
  for (int r = 0; r < 4; ++r) {
#pragma unroll
    for (int n = 0; n < 4; ++n) {
      const int hl = wc * 64 + n * 16 + lr;          // col (h)
      const float bias = b1e[hl];
#pragma unroll
      for (int j = 0; j < 4; ++j) {
        const int s = s0 + wr * 64 + r * 16 + kc4 + j;
        Hp[(size_t)s * H_ + hl] = __float2bfloat16(gelu_exact(acc[r][n][j] + bias));
      }
    }
  }
}

// ---------------- GEMM2: out[b][s][o] += g * gelu(H @ w2 + b2) ----------------
__global__ __launch_bounds__(512, 2) void gemm2_kernel(
    const __hip_bfloat16* __restrict__ Hbuf, const __hip_bfloat16* __restrict__ W2T,
    const float* __restrict__ b2, float* __restrict__ out,
    const int* __restrict__ gidx, const float* __restrict__ gwt, const int* __restrict__ psort)
{
  extern __shared__ char lds[];
  const int nblk = gridDim.x * gridDim.y;            // 512 (%8==0)
  const int P = blockIdx.y * gridDim.x + blockIdx.x;
  const int L = (P & 7) * (nblk >> 3) + (P >> 3);
  const int pairL = L >> 3;                          // 8 tiles/pair
  const int tl = L & 7;
  const int p = psort[pairL];
  const int b = p >> 1;
  const int e = gidx[p];
  const float gw = gwt[p];
  const int s0 = (tl >> 1) * 128;                    // 4 s-tiles
  const int o0 = (tl & 1) * 256;                     // 2 o-tiles
  const char* Ag = (const char*)(Hbuf + ((size_t)p * S_ + s0) * H_);
  const char* Bg = (const char*)(W2T + ((size_t)e * O_ + o0) * H_);
  f32x4 acc[4][4] = {};
  gemm128x256(Ag, Bg, H_ * 2, H_ * 2, H_ / 64, lds, acc);

  const int tid = threadIdx.x, l = tid & 63, w = tid >> 6;
  const int wr = w >> 2, wc = w & 3, lr = l & 15, kc4 = ((l >> 4) & 3) << 2;
  const float* b2e = b2 + (size_t)e * O_ + o0;
#pragma unroll
  for (int r = 0; r < 4; ++r) {
#pragma unroll
    for (int n = 0; n < 4; ++n) {
      const int ol = wc * 64 + n * 16 + lr;          // col (o)
      const float bias = b2e[ol];
#pragma unroll
      for (int j = 0; j < 4; ++j) {
        const int s = s0 + wr * 64 + r * 16 + kc4 + j;
        atomicAdd(out + ((size_t)b * S_ + s) * O_ + o0 + ol,
                  gelu_exact(acc[r][n][j] + bias) * gw);
      }
    }
  }
}

// ---------------- sentinel (ws too small signal) ----------------
__global__ void sentinel_kernel(float* out, int n) {
  int i = blockIdx.x * blockDim.x + threadIdx.x;
  for (; i < n; i += gridDim.x * blockDim.x) out[i] = 1.0e6f;
}

extern "C" void kernel_launch(void* const* d_in, const int* in_sizes, int n_in,
                              void* d_out, int out_size, void* d_ws, size_t ws_size,
                              hipStream_t stream)
{
  const float* x      = (const float*)d_in[0];
  const float* attn_w = (const float*)d_in[1];
  const float* attn_b = (const float*)d_in[2];
  const float* gate_w = (const float*)d_in[3];
  const float* gate_b = (const float*)d_in[4];
  const float* w1     = (const float*)d_in[5];
  const float* b1     = (const float*)d_in[6];
  const float* w2     = (const float*)d_in[7];
  const float* b2     = (const float*)d_in[8];
  float* out = (float*)d_out;

  char* ws = (char*)d_ws;
  const size_t OFF_GIDX = 0;     // 256 B
  const size_t OFF_GWT  = 256;   // 256 B
  const size_t OFF_PSRT = 512;   // 256 B
  const size_t OFF_X    = 1024;
  const size_t SZ_X     = (size_t)B_ * S_ * D_ * 2;   // 16 MB
  const size_t OFF_W1T  = OFF_X + SZ_X;
  const size_t SZ_W1T   = (size_t)E_ * H_ * D_ * 2;   // 16 MB
  const size_t OFF_W2T  = OFF_W1T + SZ_W1T;
  const size_t SZ_W2T   = (size_t)E_ * O_ * H_ * 2;   // 16 MB
  const size_t OFF_H    = OFF_W2T + SZ_W2T;
  const size_t PAIR_H   = (size_t)S_ * H_ * 2;        // 2 MB per pair

  if (OFF_H + 64 * PAIR_H > ws_size) {
    hipLaunchKernelGGL(sentinel_kernel, dim3(256), dim3(256), 0, stream, out, out_size);
    return;
  }

  int*   gidx  = (int*)(ws + OFF_GIDX);
  float* gwt   = (float*)(ws + OFF_GWT);
  int*   psort = (int*)(ws + OFF_PSRT);
  __hip_bfloat16* xb   = (__hip_bfloat16*)(ws + OFF_X);
  __hip_bfloat16* w1T  = (__hip_bfloat16*)(ws + OFF_W1T);
  __hip_bfloat16* w2T  = (__hip_bfloat16*)(ws + OFF_W2T);
  __hip_bfloat16* Hbuf = (__hip_bfloat16*)(ws + OFF_H);

  // 144 KiB dynamic LDS opt-in
  (void)hipFuncSetAttribute((const void*)gemm1_kernel, hipFuncAttributeMaxDynamicSharedMemorySize, 147456);
  (void)hipFuncSetAttribute((const void*)gemm2_kernel, hipFuncAttributeMaxDynamicSharedMemorySize, 147456);

  hipLaunchKernelGGL(pool_gate_kernel, dim3(B_), dim3(256), 0, stream,
                     x, attn_w, attn_b, gate_w, gate_b, gidx, gwt);
  hipLaunchKernelGGL(psort_kernel, dim3(1), dim3(64), 0, stream, gidx, psort);
  hipLaunchKernelGGL(cast_x_kernel, dim3(2048), dim3(256), 0, stream,
                     x, (ushort*)xb, B_ * S_ * D_);
  hipLaunchKernelGGL(transpose_cast_kernel, dim3(H_ / 32, D_ / 32, E_), dim3(32, 8), 0, stream,
                     w1, w1T, D_, H_);
  hipLaunchKernelGGL(transpose_cast_kernel, dim3(O_ / 32, H_ / 32, E_), dim3(32, 8), 0, stream,
                     w2, w2T, H_, O_);
  hipMemsetAsync(d_out, 0, (size_t)out_size * sizeof(float), stream);

  hipLaunchKernelGGL(gemm1_kernel, dim3(32, 64), dim3(512), 147456, stream,
                     xb, w1T, b1, Hbuf, gidx, psort);
  hipLaunchKernelGGL(gemm2_kernel, dim3(8, 64), dim3(512), 147456, stream,
                     Hbuf, w2T, b2, out, gidx, gwt, psort);
}

// Round 4
// 290.026 us; speedup vs baseline: 1.6724x; 1.1809x over previous
//
#include <hip/hip_runtime.h>
#include <hip/hip_bf16.h>
#include <math.h>

#define B_  32
#define S_  512
#define D_  512
#define E_  8
#define H_  2048
#define O_  512

typedef __bf16 bf16x8 __attribute__((ext_vector_type(8)));
typedef float  f32x4  __attribute__((ext_vector_type(4)));

#define GL2LDS(src, dst) \
  __builtin_amdgcn_global_load_lds((const __attribute__((address_space(1))) void*)(src), \
                                   (__attribute__((address_space(3))) void*)(dst), 16, 0, 0)

// tanh-form GELU: v * sigmoid(1.59577v + 0.0713548 v^3). Max |err| vs exact ~1e-3,
// well under bf16-H rounding noise. ~8 VALU ops vs ~30 for erff.
__device__ __forceinline__ float gelu_fast(float v) {
  float w = v * fmaf(v * v, 0.0713548162f, 1.5957691216f);
  float e = __expf(-w);
  return v * __builtin_amdgcn_rcpf(1.0f + e);
}

// exact erf GELU kept for reference/unused paths
__device__ __forceinline__ float gelu_exact(float v) {
  return 0.5f * v * (1.0f + erff(v * 0.70710678118654752f));
}

// ---------------- pooling + gating (unchanged, proven) ----------------
__global__ __launch_bounds__(256) void pool_gate_kernel(
    const float* __restrict__ x, const float* __restrict__ attn_w,
    const float* __restrict__ attn_b, const float* __restrict__ gate_w,
    const float* __restrict__ gate_b, int* __restrict__ gidx, float* __restrict__ gwt)
{
  __shared__ float sc[512];
  __shared__ float pooled[512];
  __shared__ float red[8];
  const int tid = threadIdx.x;
  const int b = blockIdx.x;
  const float* xb = x + (size_t)b * S_ * D_;
  const float ab = attn_b[0];

  for (int s = tid; s < S_; s += 256) {
    const float4* xr = (const float4*)(xb + (size_t)s * D_);
    const float4* wr = (const float4*)attn_w;
    float acc = 0.f;
    for (int i = 0; i < D_ / 4; ++i) {
      float4 xv = xr[i], wv = wr[i];
      acc += xv.x * wv.x + xv.y * wv.y + xv.z * wv.z + xv.w * wv.w;
    }
    sc[s] = acc + ab;
  }
  __syncthreads();

  float m = fmaxf(sc[tid], sc[tid + 256]);
  for (int off = 32; off; off >>= 1) m = fmaxf(m, __shfl_down(m, off));
  if ((tid & 63) == 0) red[tid >> 6] = m;
  __syncthreads();
  if (tid == 0) red[0] = fmaxf(fmaxf(red[0], red[1]), fmaxf(red[2], red[3]));
  __syncthreads();
  m = red[0];
  float e0 = expf(sc[tid] - m), e1 = expf(sc[tid + 256] - m);
  float ssum = e0 + e1;
  for (int off = 32; off; off >>= 1) ssum += __shfl_down(ssum, off);
  if ((tid & 63) == 0) red[4 + (tid >> 6)] = ssum;
  __syncthreads();
  if (tid == 0) red[4] = red[4] + red[5] + red[6] + red[7];
  __syncthreads();
  float inv = 1.f / red[4];
  sc[tid] = e0 * inv;
  sc[tid + 256] = e1 * inv;
  __syncthreads();

  float p0 = 0.f, p1 = 0.f;
  for (int s = 0; s < S_; ++s) {
    float awv = sc[s];
    p0 += awv * xb[(size_t)s * D_ + tid];
    p1 += awv * xb[(size_t)s * D_ + tid + 256];
  }
  pooled[tid] = p0;
  pooled[tid + 256] = p1;
  __syncthreads();

  if (tid < E_) {
    float z = gate_b[tid];
    for (int d = 0; d < D_; ++d) z += pooled[d] * gate_w[d * E_ + tid];
    red[tid] = z;
  }
  __syncthreads();
  if (tid == 0) {
    float zmax = red[0];
    for (int i = 1; i < E_; ++i) zmax = fmaxf(zmax, red[i]);
    float ge[E_]; float zs = 0.f;
    for (int i = 0; i < E_; ++i) { ge[i] = expf(red[i] - zmax); zs += ge[i]; }
    for (int i = 0; i < E_; ++i) ge[i] /= zs;
    int i0 = 0;
    for (int i = 1; i < E_; ++i) if (ge[i] > ge[i0]) i0 = i;
    int i1 = -1;
    for (int i = 0; i < E_; ++i) if (i != i0 && (i1 < 0 || ge[i] > ge[i1])) i1 = i;
    float denom = ge[i0] + ge[i1] + 1e-9f;
    gidx[b * 2 + 0] = i0; gidx[b * 2 + 1] = i1;
    gwt[b * 2 + 0] = ge[i0] / denom; gwt[b * 2 + 1] = ge[i1] / denom;
  }
}

// ---------------- sort the 64 (b,slot) pairs by expert (gemm1 L2 locality) ----
__global__ void psort_kernel(const int* __restrict__ gidx, int* __restrict__ psort) {
  if (threadIdx.x == 0 && blockIdx.x == 0) {
    int cnt[E_];
    for (int e = 0; e < E_; ++e) cnt[e] = 0;
    for (int p = 0; p < 2 * B_; ++p) cnt[gidx[p]]++;
    int pos[E_]; int s = 0;
    for (int e = 0; e < E_; ++e) { pos[e] = s; s += cnt[e]; }
    for (int p = 0; p < 2 * B_; ++p) psort[pos[gidx[p]]++] = p;
  }
}

// ---------------- x -> bf16 ----------------
__global__ void cast_x_kernel(const float* __restrict__ in, ushort* __restrict__ outp, int n) {
  int i = blockIdx.x * blockDim.x + threadIdx.x;
  const int n4 = n >> 2;
  for (; i < n4; i += gridDim.x * blockDim.x) {
    float4 v = ((const float4*)in)[i];
    ushort4 o;
    o.x = __builtin_bit_cast(unsigned short, __float2bfloat16(v.x));
    o.y = __builtin_bit_cast(unsigned short, __float2bfloat16(v.y));
    o.z = __builtin_bit_cast(unsigned short, __float2bfloat16(v.z));
    o.w = __builtin_bit_cast(unsigned short, __float2bfloat16(v.w));
    ((ushort4*)outp)[i] = o;
  }
}

// ---------------- [z][R][C] f32 -> [z][C][R] bf16 ----------------
__global__ void transpose_cast_kernel(const float* __restrict__ in,
                                      __hip_bfloat16* __restrict__ outT, int R, int C)
{
  __shared__ float tile[32][33];
  const int z = blockIdx.z;
  const float* inz = in + (size_t)z * R * C;
  __hip_bfloat16* outz = outT + (size_t)z * R * C;
  const int c0 = blockIdx.x * 32, r0 = blockIdx.y * 32;
  const int tx = threadIdx.x, ty = threadIdx.y;
#pragma unroll
  for (int jj = 0; jj < 4; ++jj) {
    int r = r0 + ty + jj * 8;
    tile[ty + jj * 8][tx] = inz[(size_t)r * C + c0 + tx];
  }
  __syncthreads();
#pragma unroll
  for (int jj = 0; jj < 4; ++jj) {
    int c = c0 + ty + jj * 8;
    outz[(size_t)c * R + r0 + tx] = __float2bfloat16(tile[tx][ty + jj * 8]);
  }
}

// =====================================================================
// GEMM core: A = 256 weight rows (-> output feature dim), B = 128 data rows
// (s). BK=64, 512 threads = 8 waves (wh=w>>1: feature quarter, ws=w&1: s half),
// acc[4][4] (r: 16-row feature subtiles, n: 16-row s subtiles).
// D-fragment mapping (HW-verified round 2): out_row(feature) =
// r*16 + ((l>>4)&3)*4 + j, out_col(s) = n*16 + (l&15).
// 3-deep LDS ring (3 x 48 KiB): compute tile t, stage tile t+2; counted
// vmcnt(9)/(6)/(0) as round 3 (proven). Weights at buf+0 (32KB, 4 chunks),
// data at buf+32768 (16KB, 2 chunks). XOR swizzle byte^=((row&7)<<4) on
// global source and on ds_read (involution).
// =====================================================================
__device__ __forceinline__ void gemm_core(const char* __restrict__ Wg, const char* __restrict__ Xg,
                                          const int ldw, const int ldx, const int NT,
                                          char* lds, f32x4 (&acc)[4][4])
{
  const int tid = threadIdx.x;
  const int l = tid & 63;
  const int w = tid >> 6;
  const int wh = w >> 1;                  // feature quarter 0..3 (64 rows)
  const int ws = w & 1;                   // s half 0..1 (64 rows)
  const int lr = l & 15;
  const int kc16 = ((l >> 4) & 3) << 4;
  const int swz = (lr & 7) << 4;
  const int kA = kc16 ^ swz;              // kh=0
  const int kB = (64 + kc16) ^ swz;       // kh=1
  const int aoff = wh * 8192 + lr * 128;            // weights region at 0
  const int boff = 32768 + ws * 8192 + lr * 128;    // data region at 32KB

  const int rw = tid >> 3;                              // row within 8KB chunk
  const int cs = ((tid & 7) << 4) ^ ((rw & 7) << 4);    // inverse-swizzled src col
  const int dst = tid * 16;
  const char* pW0 = Wg + (size_t)(rw      ) * ldw + cs;
  const char* pW1 = Wg + (size_t)(rw +  64) * ldw + cs;
  const char* pW2 = Wg + (size_t)(rw + 128) * ldw + cs;
  const char* pW3 = Wg + (size_t)(rw + 192) * ldw + cs;
  const char* pX0 = Xg + (size_t)(rw      ) * ldx + cs;
  const char* pX1 = Xg + (size_t)(rw +  64) * ldx + cs;

  // ---- prologue: stage tiles 0 (buf0) and 1 (buf1) ----
  {
    char* q0 = lds;
    GL2LDS(pW0, q0 + dst);          GL2LDS(pW1, q0 + 8192 + dst);
    GL2LDS(pW2, q0 + 16384 + dst);  GL2LDS(pW3, q0 + 24576 + dst);
    GL2LDS(pX0, q0 + 32768 + dst);  GL2LDS(pX1, q0 + 40960 + dst);
    char* q1 = lds + 49152;
    GL2LDS(pW0 + 128, q1 + dst);          GL2LDS(pW1 + 128, q1 + 8192 + dst);
    GL2LDS(pW2 + 128, q1 + 16384 + dst);  GL2LDS(pW3 + 128, q1 + 24576 + dst);
    GL2LDS(pX0 + 128, q1 + 32768 + dst);  GL2LDS(pX1 + 128, q1 + 40960 + dst);
    pW0 += 256; pW1 += 256; pW2 += 256; pW3 += 256; pX0 += 256; pX1 += 256;
  }

  for (int t = 0; t < NT; ++t) {
    char* cur = lds + (t % 3) * 49152;
    char* nb  = lds + ((t + 2) % 3) * 49152;
    const bool pre = (t + 2 < NT);

    // ---------------- phase A (kh=0) ----------------
    if (pre) {
      GL2LDS(pW0, nb + dst);
      GL2LDS(pW1, nb + 8192 + dst);
      GL2LDS(pW2, nb + 16384 + dst);
    }
    if (pre)             asm volatile("s_waitcnt vmcnt(9)" ::: "memory");
    else if (t + 1 < NT) asm volatile("s_waitcnt vmcnt(6)" ::: "memory");
    else                 asm volatile("s_waitcnt vmcnt(0)" ::: "memory");
    __builtin_amdgcn_s_barrier();
    __builtin_amdgcn_sched_barrier(0);
    {
      bf16x8 af[4], bfv[4];
#pragma unroll
      for (int r = 0; r < 4; ++r) af[r]  = *(const bf16x8*)(cur + aoff + r * 2048 + kA);
#pragma unroll
      for (int n = 0; n < 4; ++n) bfv[n] = *(const bf16x8*)(cur + boff + n * 2048 + kA);
      __builtin_amdgcn_s_setprio(1);
#pragma unroll
      for (int r = 0; r < 4; ++r)
#pragma unroll
        for (int n = 0; n < 4; ++n)
          acc[r][n] = __builtin_amdgcn_mfma_f32_16x16x32_bf16(af[r], bfv[n], acc[r][n], 0, 0, 0);
      __builtin_amdgcn_s_setprio(0);
    }
    __builtin_amdgcn_sched_barrier(0);
    __builtin_amdgcn_s_barrier();

    // ---------------- phase B (kh=1) ----------------
    if (pre) {
      GL2LDS(pW3, nb + 24576 + dst);
      GL2LDS(pX0, nb + 32768 + dst);
      GL2LDS(pX1, nb + 40960 + dst);
      pW0 += 128; pW1 += 128; pW2 += 128; pW3 += 128; pX0 += 128; pX1 += 128;
    }
    {
      bf16x8 af[4], bfv[4];
#pragma unroll
      for (int r = 0; r < 4; ++r) af[r]  = *(const bf16x8*)(cur + aoff + r * 2048 + kB);
#pragma unroll
      for (int n = 0; n < 4; ++n) bfv[n] = *(const bf16x8*)(cur + boff + n * 2048 + kB);
      __builtin_amdgcn_s_setprio(1);
#pragma unroll
      for (int r = 0; r < 4; ++r)
#pragma unroll
        for (int n = 0; n < 4; ++n)
          acc[r][n] = __builtin_amdgcn_mfma_f32_16x16x32_bf16(af[r], bfv[n], acc[r][n], 0, 0, 0);
      __builtin_amdgcn_s_setprio(0);
    }
    __builtin_amdgcn_sched_barrier(0);
    __builtin_amdgcn_s_barrier();
  }
}

// ---------------- GEMM1: H[p][s][h] = gelu(x @ w1 + b1), bf16, ushort4 stores ----
__global__ __launch_bounds__(512, 2) void gemm1_kernel(
    const __hip_bfloat16* __restrict__ Xb, const __hip_bfloat16* __restrict__ W1T,
    const float* __restrict__ b1, __hip_bfloat16* __restrict__ Hbuf,
    const int* __restrict__ gidx, const int* __restrict__ psort)
{
  extern __shared__ char lds[];
  const int nblk = gridDim.x * gridDim.y;            // 2048
  const int P = blockIdx.y * gridDim.x + blockIdx.x;
  const int L = (P & 7) * (nblk >> 3) + (P >> 3);    // bijective XCD chunk remap
  const int pairL = L >> 5;                          // 32 tiles/pair
  const int tl = L & 31;
  const int p = psort[pairL];
  const int b = p >> 1;
  const int e = gidx[p];
  const int s0 = (tl >> 3) * 128;                    // 4 s-tiles
  const int h0 = (tl & 7) * 256;                     // 8 h-tiles
  const char* Wg = (const char*)(W1T + ((size_t)e * H_ + h0) * D_);
  const char* Xg = (const char*)(Xb + ((size_t)b * S_ + s0) * D_);
  f32x4 acc[4][4] = {};
  gemm_core(Wg, Xg, D_ * 2, D_ * 2, D_ / 64, lds, acc);

  const int tid = threadIdx.x, l = tid & 63, w = tid >> 6;
  const int wh = w >> 1, ws = w & 1, lr = l & 15, hi4 = ((l >> 4) & 3) << 2;
  const float* b1e = b1 + (size_t)e * H_ + h0;
  __hip_bfloat16* Hp = Hbuf + (size_t)p * S_ * H_;
#pragma unroll
  for (int r = 0; r < 4; ++r) {
    const int hl = wh * 64 + r * 16 + hi4;           // feature offset (mult of 4)
    const float4 bias = *(const float4*)(b1e + hl);
#pragma unroll
    for (int n = 0; n < 4; ++n) {
      const int sl = s0 + ws * 64 + n * 16 + lr;     // s row
      ushort4 ov;
      ov.x = __builtin_bit_cast(unsigned short, __float2bfloat16(gelu_fast(acc[r][n][0] + bias.x)));
      ov.y = __builtin_bit_cast(unsigned short, __float2bfloat16(gelu_fast(acc[r][n][1] + bias.y)));
      ov.z = __builtin_bit_cast(unsigned short, __float2bfloat16(gelu_fast(acc[r][n][2] + bias.z)));
      ov.w = __builtin_bit_cast(unsigned short, __float2bfloat16(gelu_fast(acc[r][n][3] + bias.w)));
      *(ushort4*)(Hp + (size_t)sl * H_ + h0 + hl) = ov;
    }
  }
}

// ---------------- GEMM2 fused: out[b][s][o] = sum_slot gw * gelu(H @ w2 + b2) ----
// One block handles BOTH slots of batch b for its (s-tile, o-tile): two K-passes,
// register accumulation, single float4 stores. No atomics, no memset needed.
__global__ __launch_bounds__(512, 2) void gemm2_kernel(
    const __hip_bfloat16* __restrict__ Hbuf, const __hip_bfloat16* __restrict__ W2T,
    const float* __restrict__ b2, float* __restrict__ out,
    const int* __restrict__ gidx, const float* __restrict__ gwt)
{
  extern __shared__ char lds[];
  const int nblk = gridDim.x * gridDim.y;            // 256
  const int P = blockIdx.y * gridDim.x + blockIdx.x;
  const int L = (P & 7) * (nblk >> 3) + (P >> 3);
  const int b = L >> 3;                              // 8 tiles/batch
  const int tl = L & 7;
  const int s0 = (tl >> 1) * 128;                    // 4 s-tiles
  const int o0 = (tl & 1) * 256;                     // 2 o-tiles

  const int tid = threadIdx.x, l = tid & 63, w = tid >> 6;
  const int wh = w >> 1, ws = w & 1, lr = l & 15, hi4 = ((l >> 4) & 3) << 2;

  f32x4 fout[4][4] = {};
  for (int slot = 0; slot < 2; ++slot) {
    const int p = b * 2 + slot;
    const int e = gidx[p];
    const float gw = gwt[p];
    const char* Wg = (const char*)(W2T + ((size_t)e * O_ + o0) * H_);
    const char* Xg = (const char*)(Hbuf + ((size_t)p * S_ + s0) * H_);
    f32x4 acc[4][4] = {};
    gemm_core(Wg, Xg, H_ * 2, H_ * 2, H_ / 64, lds, acc);
    const float* b2e = b2 + (size_t)e * O_ + o0;
#pragma unroll
    for (int r = 0; r < 4; ++r) {
      const int ol = wh * 64 + r * 16 + hi4;
      const float4 bias = *(const float4*)(b2e + ol);
#pragma unroll
      for (int n = 0; n < 4; ++n) {
        fout[r][n][0] += gelu_fast(acc[r][n][0] + bias.x) * gw;
        fout[r][n][1] += gelu_fast(acc[r][n][1] + bias.y) * gw;
        fout[r][n][2] += gelu_fast(acc[r][n][2] + bias.z) * gw;
        fout[r][n][3] += gelu_fast(acc[r][n][3] + bias.w) * gw;
      }
    }
  }

#pragma unroll
  for (int r = 0; r < 4; ++r) {
    const int ol = wh * 64 + r * 16 + hi4;
#pragma unroll
    for (int n = 0; n < 4; ++n) {
      const int sl = s0 + ws * 64 + n * 16 + lr;
      *(float4*)(out + ((size_t)b * S_ + sl) * O_ + o0 + ol) =
          (float4){fout[r][n][0], fout[r][n][1], fout[r][n][2], fout[r][n][3]};
    }
  }
}

// ---------------- sentinel (ws too small signal) ----------------
__global__ void sentinel_kernel(float* out, int n) {
  int i = blockIdx.x * blockDim.x + threadIdx.x;
  for (; i < n; i += gridDim.x * blockDim.x) out[i] = 1.0e6f;
}

extern "C" void kernel_launch(void* const* d_in, const int* in_sizes, int n_in,
                              void* d_out, int out_size, void* d_ws, size_t ws_size,
                              hipStream_t stream)
{
  const float* x      = (const float*)d_in[0];
  const float* attn_w = (const float*)d_in[1];
  const float* attn_b = (const float*)d_in[2];
  const float* gate_w = (const float*)d_in[3];
  const float* gate_b = (const float*)d_in[4];
  const float* w1     = (const float*)d_in[5];
  const float* b1     = (const float*)d_in[6];
  const float* w2     = (const float*)d_in[7];
  const float* b2     = (const float*)d_in[8];
  float* out = (float*)d_out;

  char* ws = (char*)d_ws;
  const size_t OFF_GIDX = 0;     // 256 B
  const size_t OFF_GWT  = 256;   // 256 B
  const size_t OFF_PSRT = 512;   // 256 B
  const size_t OFF_X    = 1024;
  const size_t SZ_X     = (size_t)B_ * S_ * D_ * 2;   // 16 MB
  const size_t OFF_W1T  = OFF_X + SZ_X;
  const size_t SZ_W1T   = (size_t)E_ * H_ * D_ * 2;   // 16 MB
  const size_t OFF_W2T  = OFF_W1T + SZ_W1T;
  const size_t SZ_W2T   = (size_t)E_ * O_ * H_ * 2;   // 16 MB
  const size_t OFF_H    = OFF_W2T + SZ_W2T;
  const size_t PAIR_H   = (size_t)S_ * H_ * 2;        // 2 MB per pair

  if (OFF_H + 64 * PAIR_H > ws_size) {
    hipLaunchKernelGGL(sentinel_kernel, dim3(256), dim3(256), 0, stream, out, out_size);
    return;
  }

  int*   gidx  = (int*)(ws + OFF_GIDX);
  float* gwt   = (float*)(ws + OFF_GWT);
  int*   psort = (int*)(ws + OFF_PSRT);
  __hip_bfloat16* xb   = (__hip_bfloat16*)(ws + OFF_X);
  __hip_bfloat16* w1T  = (__hip_bfloat16*)(ws + OFF_W1T);
  __hip_bfloat16* w2T  = (__hip_bfloat16*)(ws + OFF_W2T);
  __hip_bfloat16* Hbuf = (__hip_bfloat16*)(ws + OFF_H);

  // 144 KiB dynamic LDS opt-in
  (void)hipFuncSetAttribute((const void*)gemm1_kernel, hipFuncAttributeMaxDynamicSharedMemorySize, 147456);
  (void)hipFuncSetAttribute((const void*)gemm2_kernel, hipFuncAttributeMaxDynamicSharedMemorySize, 147456);

  hipLaunchKernelGGL(pool_gate_kernel, dim3(B_), dim3(256), 0, stream,
                     x, attn_w, attn_b, gate_w, gate_b, gidx, gwt);
  hipLaunchKernelGGL(psort_kernel, dim3(1), dim3(64), 0, stream, gidx, psort);
  hipLaunchKernelGGL(cast_x_kernel, dim3(2048), dim3(256), 0, stream,
                     x, (ushort*)xb, B_ * S_ * D_);
  hipLaunchKernelGGL(transpose_cast_kernel, dim3(H_ / 32, D_ / 32, E_), dim3(32, 8), 0, stream,
                     w1, w1T, D_, H_);
  hipLaunchKernelGGL(transpose_cast_kernel, dim3(O_ / 32, H_ / 32, E_), dim3(32, 8), 0, stream,
                     w2, w2T, H_, O_);

  hipLaunchKernelGGL(gemm1_kernel, dim3(32, 64), dim3(512), 147456, stream,
                     xb, w1T, b1, Hbuf, gidx, psort);
  hipLaunchKernelGGL(gemm2_kernel, dim3(8, 32), dim3(512), 147456, stream,
                     Hbuf, w2T, b2, out, gidx, gwt);
}

// Round 5
// 269.260 us; speedup vs baseline: 1.8014x; 1.0771x over previous
//
#include <hip/hip_runtime.h>
#include <hip/hip_bf16.h>
#include <math.h>

#define B_  32
#define S_  512
#define D_  512
#define E_  8
#define H_  2048
#define O_  512

typedef __bf16 bf16x8 __attribute__((ext_vector_type(8)));
typedef float  f32x4  __attribute__((ext_vector_type(4)));

#define GL2LDS(src, dst) \
  __builtin_amdgcn_global_load_lds((const __attribute__((address_space(1))) void*)(src), \
                                   (__attribute__((address_space(3))) void*)(dst), 16, 0, 0)

// tanh-form GELU (proven round 4: absmax unchanged at 3.9e-3)
__device__ __forceinline__ float gelu_fast(float v) {
  float w = v * fmaf(v * v, 0.0713548162f, 1.5957691216f);
  float e = __expf(-w);
  return v * __builtin_amdgcn_rcpf(1.0f + e);
}

// ---------------- cast x -> bf16, fused attention scores ----------------
// attn_b is a scalar added to every score -> cancels in softmax; skipped.
__global__ __launch_bounds__(256) void cast_score_kernel(
    const float* __restrict__ x, const float* __restrict__ attn_w,
    ushort* __restrict__ xb, float* __restrict__ scores)
{
  const int t = threadIdx.x;
  const int r = t >> 5;               // row 0..7 within block
  const int cg = t & 31;              // 16-float column group
  const int row = blockIdx.x * 8 + r; // global (b*512+s)
  const float* src  = x + (size_t)row * D_ + cg * 16;
  const float* wsrc = attn_w + cg * 16;
  ushort* dstp = xb + (size_t)row * D_ + cg * 16;
  float acc = 0.f;
#pragma unroll
  for (int k = 0; k < 4; ++k) {
    float4 v  = *(const float4*)(src + k * 4);
    float4 wv = *(const float4*)(wsrc + k * 4);
    acc += v.x * wv.x + v.y * wv.y + v.z * wv.z + v.w * wv.w;
    ushort4 o;
    o.x = __builtin_bit_cast(unsigned short, __float2bfloat16(v.x));
    o.y = __builtin_bit_cast(unsigned short, __float2bfloat16(v.y));
    o.z = __builtin_bit_cast(unsigned short, __float2bfloat16(v.z));
    o.w = __builtin_bit_cast(unsigned short, __float2bfloat16(v.w));
    *(ushort4*)(dstp + k * 4) = o;
  }
#pragma unroll
  for (int off = 16; off; off >>= 1) acc += __shfl_xor(acc, off);
  if (cg == 0) scores[row] = acc;
}

// ---------------- softmax over S per batch -> aw ----------------
__global__ __launch_bounds__(512) void softmax_aw_kernel(
    const float* __restrict__ scores, float* __restrict__ aw)
{
  __shared__ float red[8];
  __shared__ float mm, ss;
  const int t = threadIdx.x, b = blockIdx.x;
  float v = scores[b * S_ + t];
  float m = v;
#pragma unroll
  for (int off = 32; off; off >>= 1) m = fmaxf(m, __shfl_xor(m, off));
  if ((t & 63) == 0) red[t >> 6] = m;
  __syncthreads();
  if (t == 0) {
    float a = red[0];
    for (int i = 1; i < 8; ++i) a = fmaxf(a, red[i]);
    mm = a;
  }
  __syncthreads();
  float e = expf(v - mm);
  float s = e;
#pragma unroll
  for (int off = 32; off; off >>= 1) s += __shfl_xor(s, off);
  if ((t & 63) == 0) red[t >> 6] = s;
  __syncthreads();
  if (t == 0) {
    float a = 0.f;
    for (int i = 0; i < 8; ++i) a += red[i];
    ss = 1.f / a;
  }
  __syncthreads();
  aw[b * S_ + t] = e * ss;
}

// ---------------- pooled[b,d] = sum_s aw[b,s] * x[b,s,d] ----------------
__global__ __launch_bounds__(512) void pool_kernel(
    const float* __restrict__ x, const float* __restrict__ aw, float* __restrict__ pooled)
{
  __shared__ float sm[4][128];
  const int t = threadIdx.x;
  const int dl = t & 127;
  const int sh = t >> 7;
  const int b = blockIdx.y;
  const int d = blockIdx.x * 128 + dl;
  const float* xp  = x + (size_t)b * S_ * D_ + d;
  const float* awb = aw + b * S_;
  float acc = 0.f;
#pragma unroll 4
  for (int s = sh; s < S_; s += 4)
    acc = fmaf(awb[s], xp[(size_t)s * D_], acc);
  if (sh) sm[sh][dl] = acc;
  __syncthreads();
  if (sh == 0) pooled[b * D_ + d] = acc + sm[1][dl] + sm[2][dl] + sm[3][dl];
}

// ---------------- gates + top-2 + renorm + expert-sort ----------------
__global__ __launch_bounds__(256) void gate_psort_kernel(
    const float* __restrict__ pooled, const float* __restrict__ gate_w,
    const float* __restrict__ gate_b, int* __restrict__ gidx, float* __restrict__ gwt,
    int* __restrict__ psort)
{
  __shared__ float gl[32][8];
  const int t = threadIdx.x;
  const int b = t >> 3, ee = t & 7;
  float z = gate_b[ee];
  const float* pb = pooled + b * D_;
  for (int d = 0; d < D_; ++d) z = fmaf(pb[d], gate_w[d * E_ + ee], z);
  gl[b][ee] = z;
  __syncthreads();
  if (t < 32) {
    float ge[8];
    float zmax = gl[t][0];
    for (int i = 1; i < 8; ++i) zmax = fmaxf(zmax, gl[t][i]);
    float zs = 0.f;
    for (int i = 0; i < 8; ++i) { ge[i] = expf(gl[t][i] - zmax); zs += ge[i]; }
    for (int i = 0; i < 8; ++i) ge[i] /= zs;
    int i0 = 0;
    for (int i = 1; i < 8; ++i) if (ge[i] > ge[i0]) i0 = i;
    int i1 = -1;
    for (int i = 0; i < 8; ++i) if (i != i0 && (i1 < 0 || ge[i] > ge[i1])) i1 = i;
    float denom = ge[i0] + ge[i1] + 1e-9f;
    gidx[t * 2 + 0] = i0; gidx[t * 2 + 1] = i1;
    gwt[t * 2 + 0] = ge[i0] / denom; gwt[t * 2 + 1] = ge[i1] / denom;
  }
  __syncthreads();
  if (t == 0) {
    int cnt[E_] = {}, pos[E_];
    for (int p = 0; p < 2 * B_; ++p) cnt[gidx[p]]++;
    int s = 0;
    for (int e2 = 0; e2 < E_; ++e2) { pos[e2] = s; s += cnt[e2]; }
    for (int p = 0; p < 2 * B_; ++p) psort[pos[gidx[p]]++] = p;
  }
}

// ---------------- [z][R][C] f32 -> [z][C][R] bf16 ----------------
__global__ void transpose_cast_kernel(const float* __restrict__ in,
                                      __hip_bfloat16* __restrict__ outT, int R, int C)
{
  __shared__ float tile[32][33];
  const int z = blockIdx.z;
  const float* inz = in + (size_t)z * R * C;
  __hip_bfloat16* outz = outT + (size_t)z * R * C;
  const int c0 = blockIdx.x * 32, r0 = blockIdx.y * 32;
  const int tx = threadIdx.x, ty = threadIdx.y;
#pragma unroll
  for (int jj = 0; jj < 4; ++jj) {
    int r = r0 + ty + jj * 8;
    tile[ty + jj * 8][tx] = inz[(size_t)r * C + c0 + tx];
  }
  __syncthreads();
#pragma unroll
  for (int jj = 0; jj < 4; ++jj) {
    int c = c0 + ty + jj * 8;
    outz[(size_t)c * R + r0 + tx] = __float2bfloat16(tile[tx][ty + jj * 8]);
  }
}

// =====================================================================
// Persistent-stream GEMM pieces (3-deep ring, counted vmcnt — proven r3/r4).
// Per K-tile: W 256 rows (4x8KB chunks, LDS 0..32K), X 128 rows (2x8KB,
// LDS 32K..48K). 8 waves: wh=w>>1 feature quarter, ws=w&1 s half.
// XOR swizzle byte^=((row&7)<<4) on global source and ds_read (involution).
// =====================================================================
__device__ __forceinline__ void phase_mfma(const char* cur, int aoff, int boff, int koff,
                                           f32x4 (&acc)[4][4])
{
  bf16x8 af[4], bfv[4];
#pragma unroll
  for (int r = 0; r < 4; ++r) af[r]  = *(const bf16x8*)(cur + aoff + r * 2048 + koff);
#pragma unroll
  for (int n = 0; n < 4; ++n) bfv[n] = *(const bf16x8*)(cur + boff + n * 2048 + koff);
  __builtin_amdgcn_s_setprio(1);
#pragma unroll
  for (int r = 0; r < 4; ++r)
#pragma unroll
    for (int n = 0; n < 4; ++n)
      acc[r][n] = __builtin_amdgcn_mfma_f32_16x16x32_bf16(af[r], bfv[n], acc[r][n], 0, 0, 0);
  __builtin_amdgcn_s_setprio(0);
}

// ---------------- GEMM1 persistent: block = (pair, s-tile), streams 8 h-tiles ----
__global__ __launch_bounds__(512, 2) void gemm1_kernel(
    const __hip_bfloat16* __restrict__ Xb, const __hip_bfloat16* __restrict__ W1T,
    const float* __restrict__ b1, __hip_bfloat16* __restrict__ Hbuf,
    const int* __restrict__ gidx, const int* __restrict__ psort)
{
  extern __shared__ char lds[];
  const int tid = threadIdx.x;
  const int P = blockIdx.x;                       // 0..255
  const int n_ = (P & 7) * 32 + (P >> 3);         // pair-clustered-per-XCD remap
  const int p = psort[n_ >> 2];
  const int b = p >> 1;
  const int e = gidx[p];
  const int s0 = (n_ & 3) * 128;

  const char* Wbase = (const char*)W1T + (size_t)e * H_ * D_ * 2;
  const char* Xgb   = (const char*)Xb + ((size_t)b * S_ + s0) * D_ * 2;

  const int rw = tid >> 3;
  const int laneoff = rw * (D_ * 2) + ((((tid & 7) << 4)) ^ ((rw & 7) << 4));
  const int dst = tid * 16;

  const int l = tid & 63, w = tid >> 6;
  const int wh = w >> 1, ws_ = w & 1;
  const int lr = l & 15;
  const int kc16 = ((l >> 4) & 3) << 4;
  const int swz = (lr & 7) << 4;
  const int kA = kc16 ^ swz;
  const int kB = (64 + kc16) ^ swz;
  const int aoff = wh * 8192 + lr * 128;
  const int boff = 32768 + ws_ * 8192 + lr * 128;
  const int hi4 = ((l >> 4) & 3) << 2;

#define G1_STAGE_A(us, nb) { \
    const char* wsrc = Wbase + (((us) >> 3) << 18) + (((us) & 7) << 7) + laneoff; \
    GL2LDS(wsrc,          (nb) + dst); \
    GL2LDS(wsrc + 65536,  (nb) + 8192 + dst); \
    GL2LDS(wsrc + 131072, (nb) + 16384 + dst); }
#define G1_STAGE_B(us, nb) { \
    const char* wsrc = Wbase + (((us) >> 3) << 18) + (((us) & 7) << 7) + laneoff; \
    GL2LDS(wsrc + 196608, (nb) + 24576 + dst); \
    const char* xsrc = Xgb + (((us) & 7) << 7) + laneoff; \
    GL2LDS(xsrc,          (nb) + 32768 + dst); \
    GL2LDS(xsrc + 65536,  (nb) + 40960 + dst); }

  f32x4 acc[4][4] = {};
  __hip_bfloat16* Hp = Hbuf + (size_t)p * S_ * H_;
  const float* b1e0 = b1 + (size_t)e * H_;

  G1_STAGE_A(0, lds); G1_STAGE_B(0, lds);
  G1_STAGE_A(1, lds + 49152); G1_STAGE_B(1, lds + 49152);

  int cu = 0;
#pragma unroll 1
  for (int u = 0; u < 64; ++u) {
    char* cur = lds + cu * 49152;
    char* nb  = lds + ((cu >= 1) ? (cu - 1) : (cu + 2)) * 49152;
    if (u < 62) {
      G1_STAGE_A(u + 2, nb);
      asm volatile("s_waitcnt vmcnt(9)" ::: "memory");
    } else if (u == 62) {
      asm volatile("s_waitcnt vmcnt(6)" ::: "memory");
    } else {
      asm volatile("s_waitcnt vmcnt(0)" ::: "memory");
    }
    __builtin_amdgcn_s_barrier();
    __builtin_amdgcn_sched_barrier(0);
    phase_mfma(cur, aoff, boff, kA, acc);
    __builtin_amdgcn_sched_barrier(0);
    __builtin_amdgcn_s_barrier();
    if (u < 62) G1_STAGE_B(u + 2, nb);
    phase_mfma(cur, aoff, boff, kB, acc);
    __builtin_amdgcn_sched_barrier(0);
    __builtin_amdgcn_s_barrier();

    if ((u & 7) == 7) {               // output tile j = u>>3 complete
      const int h0 = (u >> 3) << 8;
      const float* b1e = b1e0 + h0;
#pragma unroll
      for (int r = 0; r < 4; ++r) {
        const int hl = wh * 64 + r * 16 + hi4;
        const float4 bias = *(const float4*)(b1e + hl);
#pragma unroll
        for (int n = 0; n < 4; ++n) {
          const int sl = s0 + ws_ * 64 + n * 16 + lr;
          ushort4 ov;
          ov.x = __builtin_bit_cast(unsigned short, __float2bfloat16(gelu_fast(acc[r][n][0] + bias.x)));
          ov.y = __builtin_bit_cast(unsigned short, __float2bfloat16(gelu_fast(acc[r][n][1] + bias.y)));
          ov.z = __builtin_bit_cast(unsigned short, __float2bfloat16(gelu_fast(acc[r][n][2] + bias.z)));
          ov.w = __builtin_bit_cast(unsigned short, __float2bfloat16(gelu_fast(acc[r][n][3] + bias.w)));
          *(ushort4*)(Hp + (size_t)sl * H_ + h0 + hl) = ov;
          acc[r][n] = (f32x4){0.f, 0.f, 0.f, 0.f};
        }
      }
    }
    cu = (cu == 2) ? 0 : cu + 1;
  }
#undef G1_STAGE_A
#undef G1_STAGE_B
}

// ---------------- GEMM2 persistent: block = (batch, s-tile, o-tile), streams both slots ----
__global__ __launch_bounds__(512, 2) void gemm2_kernel(
    const __hip_bfloat16* __restrict__ Hbuf, const __hip_bfloat16* __restrict__ W2T,
    const float* __restrict__ b2, float* __restrict__ out,
    const int* __restrict__ gidx, const float* __restrict__ gwt)
{
  extern __shared__ char lds[];
  const int tid = threadIdx.x;
  const int P = blockIdx.x;                       // 0..255
  const int n_ = (P & 7) * 32 + (P >> 3);         // batch-clustered-per-XCD remap
  const int b = n_ >> 3;
  const int tl = n_ & 7;
  const int s0 = (tl >> 1) * 128;
  const int o0 = (tl & 1) * 256;

  const int e0 = gidx[2 * b], e1 = gidx[2 * b + 1];
  const float gw0 = gwt[2 * b], gw1 = gwt[2 * b + 1];

  const int rw = tid >> 3;
  const int laneoff = rw * (H_ * 2) + ((((tid & 7) << 4)) ^ ((rw & 7) << 4));
  const int dst = tid * 16;

  const char* W0p = (const char*)W2T + ((size_t)e0 * O_ + o0) * H_ * 2;
  const char* W1p = (const char*)W2T + ((size_t)e1 * O_ + o0) * H_ * 2;
  const char* X0p = (const char*)Hbuf + ((size_t)(2 * b)     * S_ + s0) * H_ * 2;
  const char* X1p = (const char*)Hbuf + ((size_t)(2 * b + 1) * S_ + s0) * H_ * 2;

  const int l = tid & 63, w = tid >> 6;
  const int wh = w >> 1, ws_ = w & 1;
  const int lr = l & 15;
  const int kc16 = ((l >> 4) & 3) << 4;
  const int swz = (lr & 7) << 4;
  const int kA = kc16 ^ swz;
  const int kB = (64 + kc16) ^ swz;
  const int aoff = wh * 8192 + lr * 128;
  const int boff = 32768 + ws_ * 8192 + lr * 128;
  const int hi4 = ((l >> 4) & 3) << 2;

#define G2_STAGE_A(us, nb) { \
    const char* wsrc = (((us) & 32) ? W1p : W0p) + (((us) & 31) << 7) + laneoff; \
    GL2LDS(wsrc,          (nb) + dst); \
    GL2LDS(wsrc + 262144, (nb) + 8192 + dst); \
    GL2LDS(wsrc + 524288, (nb) + 16384 + dst); }
#define G2_STAGE_B(us, nb) { \
    const char* wsrc = (((us) & 32) ? W1p : W0p) + (((us) & 31) << 7) + laneoff; \
    GL2LDS(wsrc + 786432, (nb) + 24576 + dst); \
    const char* xsrc = (((us) & 32) ? X1p : X0p) + (((us) & 31) << 7) + laneoff; \
    GL2LDS(xsrc,          (nb) + 32768 + dst); \
    GL2LDS(xsrc + 262144, (nb) + 40960 + dst); }

  f32x4 acc[4][4] = {};
  f32x4 fout[4][4] = {};

  G2_STAGE_A(0, lds); G2_STAGE_B(0, lds);
  G2_STAGE_A(1, lds + 49152); G2_STAGE_B(1, lds + 49152);

  int cu = 0;
#pragma unroll 1
  for (int u = 0; u < 64; ++u) {
    char* cur = lds + cu * 49152;
    char* nb  = lds + ((cu >= 1) ? (cu - 1) : (cu + 2)) * 49152;
    if (u < 62) {
      G2_STAGE_A(u + 2, nb);
      asm volatile("s_waitcnt vmcnt(9)" ::: "memory");
    } else if (u == 62) {
      asm volatile("s_waitcnt vmcnt(6)" ::: "memory");
    } else {
      asm volatile("s_waitcnt vmcnt(0)" ::: "memory");
    }
    __builtin_amdgcn_s_barrier();
    __builtin_amdgcn_sched_barrier(0);
    phase_mfma(cur, aoff, boff, kA, acc);
    __builtin_amdgcn_sched_barrier(0);
    __builtin_amdgcn_s_barrier();
    if (u < 62) G2_STAGE_B(u + 2, nb);
    phase_mfma(cur, aoff, boff, kB, acc);
    __builtin_amdgcn_sched_barrier(0);
    __builtin_amdgcn_s_barrier();

    if ((u & 31) == 31) {             // slot complete: register-only gelu+accumulate
      const int slot = u >> 5;
      const float gw = slot ? gw1 : gw0;
      const float* b2e = b2 + (size_t)(slot ? e1 : e0) * O_ + o0;
#pragma unroll
      for (int r = 0; r < 4; ++r) {
        const int ol = wh * 64 + r * 16 + hi4;
        const float4 bias = *(const float4*)(b2e + ol);
#pragma unroll
        for (int n = 0; n < 4; ++n) {
          fout[r][n][0] += gelu_fast(acc[r][n][0] + bias.x) * gw;
          fout[r][n][1] += gelu_fast(acc[r][n][1] + bias.y) * gw;
          fout[r][n][2] += gelu_fast(acc[r][n][2] + bias.z) * gw;
          fout[r][n][3] += gelu_fast(acc[r][n][3] + bias.w) * gw;
          acc[r][n] = (f32x4){0.f, 0.f, 0.f, 0.f};
        }
      }
    }
    cu = (cu == 2) ? 0 : cu + 1;
  }
#undef G2_STAGE_A
#undef G2_STAGE_B

#pragma unroll
  for (int r = 0; r < 4; ++r) {
    const int ol = wh * 64 + r * 16 + hi4;
#pragma unroll
    for (int n = 0; n < 4; ++n) {
      const int sl = s0 + ws_ * 64 + n * 16 + lr;
      *(float4*)(out + ((size_t)b * S_ + sl) * O_ + o0 + ol) =
          (float4){fout[r][n][0], fout[r][n][1], fout[r][n][2], fout[r][n][3]};
    }
  }
}

// ---------------- sentinel (ws too small signal) ----------------
__global__ void sentinel_kernel(float* out, int n) {
  int i = blockIdx.x * blockDim.x + threadIdx.x;
  for (; i < n; i += gridDim.x * blockDim.x) out[i] = 1.0e6f;
}

extern "C" void kernel_launch(void* const* d_in, const int* in_sizes, int n_in,
                              void* d_out, int out_size, void* d_ws, size_t ws_size,
                              hipStream_t stream)
{
  const float* x      = (const float*)d_in[0];
  const float* attn_w = (const float*)d_in[1];
  // d_in[2] = attn_b: scalar, softmax-invariant -> unused
  const float* gate_w = (const float*)d_in[3];
  const float* gate_b = (const float*)d_in[4];
  const float* w1     = (const float*)d_in[5];
  const float* b1     = (const float*)d_in[6];
  const float* w2     = (const float*)d_in[7];
  const float* b2     = (const float*)d_in[8];
  float* out = (float*)d_out;

  char* ws = (char*)d_ws;
  const size_t OFF_GIDX = 0;     // 256 B
  const size_t OFF_GWT  = 256;   // 256 B
  const size_t OFF_PSRT = 512;   // 256 B
  const size_t OFF_X    = 1024;
  const size_t SZ_X     = (size_t)B_ * S_ * D_ * 2;   // 16 MB
  const size_t OFF_W1T  = OFF_X + SZ_X;
  const size_t SZ_W1T   = (size_t)E_ * H_ * D_ * 2;   // 16 MB
  const size_t OFF_W2T  = OFF_W1T + SZ_W1T;
  const size_t SZ_W2T   = (size_t)E_ * O_ * H_ * 2;   // 16 MB
  const size_t OFF_H    = OFF_W2T + SZ_W2T;
  const size_t PAIR_H   = (size_t)S_ * H_ * 2;        // 2 MB per pair

  if (OFF_H + 64 * PAIR_H > ws_size) {
    hipLaunchKernelGGL(sentinel_kernel, dim3(256), dim3(256), 0, stream, out, out_size);
    return;
  }

  int*   gidx  = (int*)(ws + OFF_GIDX);
  float* gwt   = (float*)(ws + OFF_GWT);
  int*   psort = (int*)(ws + OFF_PSRT);
  __hip_bfloat16* xb   = (__hip_bfloat16*)(ws + OFF_X);
  __hip_bfloat16* w1T  = (__hip_bfloat16*)(ws + OFF_W1T);
  __hip_bfloat16* w2T  = (__hip_bfloat16*)(ws + OFF_W2T);
  __hip_bfloat16* Hbuf = (__hip_bfloat16*)(ws + OFF_H);
  // pool-chain scratch overlaid on Hbuf region (consumed before gemm1 writes it)
  float* scores = (float*)(ws + OFF_H);            // 64 KB
  float* aw     = (float*)(ws + OFF_H + 65536);    // 64 KB
  float* pooled = (float*)(ws + OFF_H + 131072);   // 64 KB

  (void)hipFuncSetAttribute((const void*)gemm1_kernel, hipFuncAttributeMaxDynamicSharedMemorySize, 147456);
  (void)hipFuncSetAttribute((const void*)gemm2_kernel, hipFuncAttributeMaxDynamicSharedMemorySize, 147456);

  hipLaunchKernelGGL(cast_score_kernel, dim3(B_ * S_ / 8), dim3(256), 0, stream,
                     x, attn_w, (ushort*)xb, scores);
  hipLaunchKernelGGL(softmax_aw_kernel, dim3(B_), dim3(512), 0, stream, scores, aw);
  hipLaunchKernelGGL(pool_kernel, dim3(4, B_), dim3(512), 0, stream, x, aw, pooled);
  hipLaunchKernelGGL(gate_psort_kernel, dim3(1), dim3(256), 0, stream,
                     pooled, gate_w, gate_b, gidx, gwt, psort);
  hipLaunchKernelGGL(transpose_cast_kernel, dim3(H_ / 32, D_ / 32, E_), dim3(32, 8), 0, stream,
                     w1, w1T, D_, H_);
  hipLaunchKernelGGL(transpose_cast_kernel, dim3(O_ / 32, H_ / 32, E_), dim3(32, 8), 0, stream,
                     w2, w2T, H_, O_);

  hipLaunchKernelGGL(gemm1_kernel, dim3(256), dim3(512), 147456, stream,
                     xb, w1T, b1, Hbuf, gidx, psort);
  hipLaunchKernelGGL(gemm2_kernel, dim3(256), dim3(512), 147456, stream,
                     Hbuf, w2T, b2, out, gidx, gwt);
}